// Round 1
// baseline (202.274 us; speedup 1.0000x reference)
//
#include <hip/hip_runtime.h>

#define BATCH 8
#define NHEADS 32
#define HDIM 128
#define KVLEN 4096
#define SCALE 0.08838834764831843f   // 128^-0.5

constexpr int THREADS = 1024;
constexpr int GROUPS  = THREADS / 32;   // 32 half-wave groups
constexpr int H4      = HDIM / 4;       // 32 float4 per row

__global__ __launch_bounds__(THREADS) void attn_decode_kernel(
    const float* __restrict__ q, const float* __restrict__ k,
    const float* __restrict__ v, const float* __restrict__ mask,
    float* __restrict__ out)
{
    __shared__ float s_scores[KVLEN];        // 16 KB
    __shared__ float s_red[THREADS];         // 4 KB
    __shared__ float s_part[GROUPS * HDIM];  // 16 KB

    const int bn  = blockIdx.x;              // 0..B*N-1
    const int b   = bn / NHEADS;
    const int tid = threadIdx.x;
    const int grp = tid >> 5;                // 0..31
    const int l32 = tid & 31;                // lane within half-wave group

    const float4* __restrict__ K4 = (const float4*)k;
    const float4* __restrict__ V4 = (const float4*)v;
    const float4* __restrict__ Q4 = (const float4*)q;

    const size_t base4 = (size_t)bn * KVLEN * H4;
    const float4 q4 = Q4[(size_t)bn * H4 + l32];
    const float* __restrict__ mrow = mask + (size_t)b * KVLEN;

    // ---- Pass 1: scores[k] = SCALE * (q . K[k]) + mask[k], track max ----
    float mloc = -3.4e38f;
    for (int kk = grp; kk < KVLEN; kk += GROUPS) {
        const float4 kv4 = K4[base4 + (size_t)kk * H4 + l32];
        float p = q4.x * kv4.x + q4.y * kv4.y + q4.z * kv4.z + q4.w * kv4.w;
        p += __shfl_xor(p, 16);
        p += __shfl_xor(p, 8);
        p += __shfl_xor(p, 4);
        p += __shfl_xor(p, 2);
        p += __shfl_xor(p, 1);
        const float s = p * SCALE + mrow[kk];
        mloc = fmaxf(mloc, s);
        if (l32 == 0) s_scores[kk] = s;
    }
    s_red[tid] = mloc;
    __syncthreads();
    for (int s = THREADS / 2; s > 0; s >>= 1) {
        if (tid < s) s_red[tid] = fmaxf(s_red[tid], s_red[tid + s]);
        __syncthreads();
    }
    const float m = s_red[0];
    __syncthreads();

    // ---- exp + sum (scores live in LDS) ----
    float sloc = 0.f;
    for (int kk = tid; kk < KVLEN; kk += THREADS) {
        const float p = __expf(s_scores[kk] - m);
        s_scores[kk] = p;
        sloc += p;
    }
    s_red[tid] = sloc;
    __syncthreads();
    for (int s = THREADS / 2; s > 0; s >>= 1) {
        if (tid < s) s_red[tid] += s_red[tid + s];
        __syncthreads();
    }
    const float inv = 1.0f / s_red[0];

    // ---- Pass 2: out = (P . V) * inv ----
    float a0 = 0.f, a1 = 0.f, a2 = 0.f, a3 = 0.f;
    for (int kk = grp; kk < KVLEN; kk += GROUPS) {
        const float p = s_scores[kk];                         // LDS broadcast
        const float4 v4 = V4[base4 + (size_t)kk * H4 + l32];
        a0 += p * v4.x; a1 += p * v4.y; a2 += p * v4.z; a3 += p * v4.w;
    }
    float* pp = s_part + grp * HDIM + l32 * 4;
    pp[0] = a0; pp[1] = a1; pp[2] = a2; pp[3] = a3;
    __syncthreads();
    if (tid < HDIM) {
        float acc = 0.f;
        #pragma unroll
        for (int g = 0; g < GROUPS; ++g) acc += s_part[g * HDIM + tid];
        out[(size_t)bn * HDIM + tid] = acc * inv;
    }
}

extern "C" void kernel_launch(void* const* d_in, const int* in_sizes, int n_in,
                              void* d_out, int out_size, void* d_ws, size_t ws_size,
                              hipStream_t stream) {
    const float* q    = (const float*)d_in[0];
    const float* k    = (const float*)d_in[1];
    const float* v    = (const float*)d_in[2];
    const float* mask = (const float*)d_in[3];
    float* out = (float*)d_out;

    attn_decode_kernel<<<BATCH * NHEADS, THREADS, 0, stream>>>(q, k, v, mask, out);
}

// Round 2
// 185.512 us; speedup vs baseline: 1.0904x; 1.0904x over previous
//
#include <hip/hip_runtime.h>

#define BATCH 8
#define NHEADS 32
#define HDIM 128
#define KVLEN 4096
#define SCALE 0.08838834764831843f   // 128^-0.5

constexpr int THREADS = 1024;
constexpr int GROUPS  = THREADS / 32;   // 32 half-wave groups per WG
constexpr int H4      = HDIM / 4;       // 32 float4 per row
constexpr int ITERS   = KVLEN / GROUPS; // 128 keys per group

__global__ __launch_bounds__(THREADS) void attn_decode_online(
    const float* __restrict__ q, const float* __restrict__ k,
    const float* __restrict__ v, const float* __restrict__ mask,
    float* __restrict__ out)
{
    __shared__ float s_m[GROUPS];
    __shared__ float s_l[GROUPS];
    __shared__ float s_acc[GROUPS * HDIM];   // 16 KB

    const int bn  = blockIdx.x;              // head index 0..255
    const int b   = bn / NHEADS;
    const int tid = threadIdx.x;
    const int grp = tid >> 5;                // 0..31
    const int l32 = tid & 31;                // lane within group

    const float4* __restrict__ K4 = (const float4*)k;
    const float4* __restrict__ V4 = (const float4*)v;
    const float4* __restrict__ Q4 = (const float4*)q;

    const size_t base4 = (size_t)bn * KVLEN * H4;
    const float4 q4 = Q4[(size_t)bn * H4 + l32];
    const float* __restrict__ mrow = mask + (size_t)b * KVLEN;

    // ---- single streaming pass: online softmax, K and V together ----
    float m = -3.0e38f, l = 0.f;
    float a0 = 0.f, a1 = 0.f, a2 = 0.f, a3 = 0.f;

    #pragma unroll 2
    for (int i = 0; i < ITERS; ++i) {
        const int kk = grp + i * GROUPS;
        const size_t roff = base4 + (size_t)kk * H4 + l32;
        const float4 kv4 = K4[roff];
        const float4 vv4 = V4[roff];

        float p = q4.x * kv4.x + q4.y * kv4.y + q4.z * kv4.z + q4.w * kv4.w;
        p += __shfl_xor(p, 16);
        p += __shfl_xor(p, 8);
        p += __shfl_xor(p, 4);
        p += __shfl_xor(p, 2);
        p += __shfl_xor(p, 1);

        const float s    = p * SCALE + mrow[kk];
        const float mnew = fmaxf(m, s);
        const float c    = __expf(m - mnew);   // rescale old state
        const float pe   = __expf(s - mnew);
        l  = l * c + pe;
        a0 = a0 * c + pe * vv4.x;
        a1 = a1 * c + pe * vv4.y;
        a2 = a2 * c + pe * vv4.z;
        a3 = a3 * c + pe * vv4.w;
        m  = mnew;
    }

    // ---- stash per-group state ----
    float* pp = s_acc + grp * HDIM + l32 * 4;
    pp[0] = a0; pp[1] = a1; pp[2] = a2; pp[3] = a3;
    if (l32 == 0) { s_m[grp] = m; s_l[grp] = l; }
    __syncthreads();

    // ---- combine 32 group states (threads 0..127, one per output dim) ----
    if (tid < HDIM) {
        float M = -3.0e38f;
        #pragma unroll
        for (int g = 0; g < GROUPS; ++g) M = fmaxf(M, s_m[g]);
        float denom = 0.f, acc = 0.f;
        #pragma unroll
        for (int g = 0; g < GROUPS; ++g) {
            const float w = __expf(s_m[g] - M);
            denom += s_l[g] * w;
            acc   += s_acc[g * HDIM + tid] * w;
        }
        out[(size_t)bn * HDIM + tid] = acc / denom;
    }
}

extern "C" void kernel_launch(void* const* d_in, const int* in_sizes, int n_in,
                              void* d_out, int out_size, void* d_ws, size_t ws_size,
                              hipStream_t stream) {
    const float* q    = (const float*)d_in[0];
    const float* k    = (const float*)d_in[1];
    const float* v    = (const float*)d_in[2];
    const float* mask = (const float*)d_in[3];
    float* out = (float*)d_out;

    attn_decode_online<<<BATCH * NHEADS, THREADS, 0, stream>>>(q, k, v, mask, out);
}

// Round 4
// 163.796 us; speedup vs baseline: 1.2349x; 1.1326x over previous
//
#include <hip/hip_runtime.h>

#define BATCH 8
#define NHEADS 32
#define HDIM 128
#define KVLEN 4096
#define SCALE 0.08838834764831843f   // 128^-0.5

typedef float f32x4 __attribute__((ext_vector_type(4)));

constexpr int THREADS = 1024;
constexpr int GROUPS  = THREADS / 32;       // 32 half-wave groups per WG
constexpr int H4      = HDIM / 4;           // 32 float4 per row
constexpr int KB      = 4;                  // keys per group per macro-iter
constexpr int MITERS  = KVLEN / (GROUPS * KB);  // 32

__global__ __launch_bounds__(THREADS) void attn_decode_online(
    const float* __restrict__ q, const float* __restrict__ k,
    const float* __restrict__ v, const float* __restrict__ mask,
    float* __restrict__ out)
{
    __shared__ float s_mask[KVLEN];          // 16 KB
    __shared__ float s_m[GROUPS];
    __shared__ float s_l[GROUPS];
    __shared__ float s_acc[GROUPS * HDIM];   // 16 KB

    const int bn  = blockIdx.x;              // head index 0..255
    const int b   = bn / NHEADS;
    const int tid = threadIdx.x;
    const int grp = tid >> 5;                // 0..31
    const int l32 = tid & 31;                // lane within group

    const f32x4* __restrict__ K4 = (const f32x4*)k;
    const f32x4* __restrict__ V4 = (const f32x4*)v;
    const f32x4* __restrict__ Q4 = (const f32x4*)q;

    // preload mask row into LDS: 1024 threads x float4 = 16 KB
    ((f32x4*)s_mask)[tid] = ((const f32x4*)(mask + (size_t)b * KVLEN))[tid];

    const size_t base4 = (size_t)bn * KVLEN * H4;
    const f32x4 q4 = Q4[(size_t)bn * H4 + l32];
    __syncthreads();

    // ---- single streaming pass: batched online softmax ----
    float m = -3.0e38f, l = 0.f;
    float a0 = 0.f, a1 = 0.f, a2 = 0.f, a3 = 0.f;

    for (int i = 0; i < MITERS; ++i) {
        const int k0 = grp + i * (GROUPS * KB);

        f32x4 kr[KB], vr[KB];
        #pragma unroll
        for (int j = 0; j < KB; ++j) {
            const size_t roff = base4 + (size_t)(k0 + j * GROUPS) * H4 + l32;
            kr[j] = __builtin_nontemporal_load(&K4[roff]);
            vr[j] = __builtin_nontemporal_load(&V4[roff]);
        }

        float s[KB];
        #pragma unroll
        for (int j = 0; j < KB; ++j) {
            float p = kr[j].x * q4.x + kr[j].y * q4.y
                    + kr[j].z * q4.z + kr[j].w * q4.w;
            p += __shfl_xor(p, 16);
            p += __shfl_xor(p, 8);
            p += __shfl_xor(p, 4);
            p += __shfl_xor(p, 2);
            p += __shfl_xor(p, 1);
            s[j] = p * SCALE + s_mask[k0 + j * GROUPS];
        }

        const float bmax = fmaxf(fmaxf(s[0], s[1]), fmaxf(s[2], s[3]));
        const float mnew = fmaxf(m, bmax);
        const float c    = __expf(m - mnew);     // single rescale per 4 keys
        float pe[KB];
        #pragma unroll
        for (int j = 0; j < KB; ++j) pe[j] = __expf(s[j] - mnew);

        l  = l * c + (pe[0] + pe[1] + pe[2] + pe[3]);
        a0 = a0 * c + pe[0]*vr[0].x + pe[1]*vr[1].x + pe[2]*vr[2].x + pe[3]*vr[3].x;
        a1 = a1 * c + pe[0]*vr[0].y + pe[1]*vr[1].y + pe[2]*vr[2].y + pe[3]*vr[3].y;
        a2 = a2 * c + pe[0]*vr[0].z + pe[1]*vr[1].z + pe[2]*vr[2].z + pe[3]*vr[3].z;
        a3 = a3 * c + pe[0]*vr[0].w + pe[1]*vr[1].w + pe[2]*vr[2].w + pe[3]*vr[3].w;
        m  = mnew;
    }

    // ---- stash per-group state ----
    float* pp = s_acc + grp * HDIM + l32 * 4;
    pp[0] = a0; pp[1] = a1; pp[2] = a2; pp[3] = a3;
    if (l32 == 0) { s_m[grp] = m; s_l[grp] = l; }
    __syncthreads();

    // ---- combine 32 group states (threads 0..127, one per output dim) ----
    if (tid < HDIM) {
        float M = -3.0e38f;
        #pragma unroll
        for (int g = 0; g < GROUPS; ++g) M = fmaxf(M, s_m[g]);
        float denom = 0.f, acc = 0.f;
        #pragma unroll
        for (int g = 0; g < GROUPS; ++g) {
            const float w = __expf(s_m[g] - M);
            denom += s_l[g] * w;
            acc   += s_acc[g * HDIM + tid] * w;
        }
        out[(size_t)bn * HDIM + tid] = acc / denom;
    }
}

extern "C" void kernel_launch(void* const* d_in, const int* in_sizes, int n_in,
                              void* d_out, int out_size, void* d_ws, size_t ws_size,
                              hipStream_t stream) {
    const float* q    = (const float*)d_in[0];
    const float* k    = (const float*)d_in[1];
    const float* v    = (const float*)d_in[2];
    const float* mask = (const float*)d_in[3];
    float* out = (float*)d_out;

    attn_decode_online<<<BATCH * NHEADS, THREADS, 0, stream>>>(q, k, v, mask, out);
}